// Round 12
// baseline (94.561 us; speedup 1.0000x reference)
//
#include <hip/hip_runtime.h>
#include <hip/hip_bf16.h>
#include <stdint.h>

#define D_MODEL 256
#define NHEAD   8
#define DK      32
#define BATCH   4
#define SEQ     2048
#define MROWS   (BATCH*SEQ)   // 8192

typedef float  f32x4  __attribute__((ext_vector_type(4)));
typedef __bf16 bf16x8 __attribute__((ext_vector_type(8)));

__device__ __forceinline__ unsigned short f2bf(float f) {
  unsigned int u = __float_as_uint(f);
  unsigned int r = (u + 0x7FFFu + ((u >> 16) & 1u)) >> 16;
  return (unsigned short)r;
}
__device__ __forceinline__ float bfbits2f(unsigned short b) {
  return __uint_as_float(((unsigned int)b) << 16);
}

__device__ __forceinline__ f32x4 mfma16(bf16x8 a, bf16x8 b, f32x4 c) {
  return __builtin_amdgcn_mfma_f32_16x16x32_bf16(a, b, c, 0, 0, 0);
}
__device__ __forceinline__ unsigned int cvtpk(float lo, float hi) {
  unsigned int r;
  asm("v_cvt_pk_bf16_f32 %0, %1, %2" : "=v"(r) : "v"(lo), "v"(hi));
  return r;
}

// scale folded into Wq/bq: (1/sqrt(32)) * log2(e)
#define QSCALE 0.2550599440097021f

// ---------------- prep: W fp32->bf16 casts + coordinate weights --------------
__global__ void prep_kernel(const float* __restrict__ cx,
                            const float* __restrict__ Wq, const float* __restrict__ Wk,
                            const float* __restrict__ Wv, const float* __restrict__ Wo,
                            unsigned short* __restrict__ Wqb, unsigned short* __restrict__ Wkb,
                            unsigned short* __restrict__ Wvb, unsigned short* __restrict__ Wob,
                            unsigned short* __restrict__ wb) {
  int tid = blockIdx.x * blockDim.x + threadIdx.x;
  int nthr = gridDim.x * blockDim.x;
  const int nw4 = (D_MODEL * D_MODEL) / 4;  // 16384
  for (int i = tid; i < nw4; i += nthr) {
    float4 a = reinterpret_cast<const float4*>(Wq)[i];
    ushort4 oa; oa.x = f2bf(a.x * QSCALE); oa.y = f2bf(a.y * QSCALE);
    oa.z = f2bf(a.z * QSCALE); oa.w = f2bf(a.w * QSCALE);
    reinterpret_cast<ushort4*>(Wqb)[i] = oa;
    float4 b = reinterpret_cast<const float4*>(Wk)[i];
    ushort4 ob; ob.x = f2bf(b.x); ob.y = f2bf(b.y); ob.z = f2bf(b.z); ob.w = f2bf(b.w);
    reinterpret_cast<ushort4*>(Wkb)[i] = ob;
    float4 c = reinterpret_cast<const float4*>(Wv)[i];
    ushort4 oc; oc.x = f2bf(c.x); oc.y = f2bf(c.y); oc.z = f2bf(c.z); oc.w = f2bf(c.w);
    reinterpret_cast<ushort4*>(Wvb)[i] = oc;
    float4 d = reinterpret_cast<const float4*>(Wo)[i];
    ushort4 od; od.x = f2bf(d.x); od.y = f2bf(d.y); od.z = f2bf(d.z); od.w = f2bf(d.w);
    reinterpret_cast<ushort4*>(Wob)[i] = od;
  }
  for (int i = tid; i < SEQ; i += nthr)
    wb[i] = (i == 0) ? (unsigned short)0 : f2bf(fabsf(cx[i] - cx[i - 1]));
}

// ---------------- fused QKV projection GEMM (x cast fused in staging) --------
// Q/K out: [bh][s][32]; V out: transposed + w-scaled: Vt[bh][d][s] = w_s * V[s][d].
__global__ __launch_bounds__(256) void qkv_gemm(
    const float* __restrict__ x,
    const unsigned short* __restrict__ Wqb, const unsigned short* __restrict__ Wkb,
    const unsigned short* __restrict__ Wvb,
    const float* __restrict__ bq, const float* __restrict__ bk_, const float* __restrict__ bv,
    const unsigned short* __restrict__ wb,
    unsigned short* __restrict__ Qb, unsigned short* __restrict__ Kb, unsigned short* __restrict__ Vt) {
  __shared__ __align__(16) unsigned short As[128 * 72];
  __shared__ __align__(16) unsigned short Bs[128 * 72];
  const int tid = threadIdx.x, lane = tid & 63, wid = tid >> 6;
  const int bm = blockIdx.x * 128;
  const int mat = blockIdx.y >> 1;
  const int ncol = (blockIdx.y & 1) * 128;
  const unsigned short* Wb = (mat == 0) ? Wqb : ((mat == 1) ? Wkb : Wvb);
  const float* bias = (mat == 0) ? bq : ((mat == 1) ? bk_ : bv);
  const float bscale = (mat == 0) ? QSCALE : 1.0f;
  const int waveM = (wid >> 1) * 64, waveN = (wid & 1) * 64;

  f32x4 acc[4][4] = {};
  for (int kt = 0; kt < 4; ++kt) {
    __syncthreads();
#pragma unroll
    for (int p = 0; p < 4; ++p) {
      int c = p * 256 + tid;
      int r = c >> 3, kc = c & 7;
      const float* xp = x + (size_t)(bm + r) * 256 + kt * 64 + kc * 8;
      float4 f0 = *reinterpret_cast<const float4*>(xp);
      float4 f1 = *reinterpret_cast<const float4*>(xp + 4);
      ushort4 h0, h1;
      h0.x = f2bf(f0.x); h0.y = f2bf(f0.y); h0.z = f2bf(f0.z); h0.w = f2bf(f0.w);
      h1.x = f2bf(f1.x); h1.y = f2bf(f1.y); h1.z = f2bf(f1.z); h1.w = f2bf(f1.w);
      *reinterpret_cast<ushort4*>(&As[r * 72 + kc * 8])     = h0;
      *reinterpret_cast<ushort4*>(&As[r * 72 + kc * 8 + 4]) = h1;
      uint4 vb = *reinterpret_cast<const uint4*>(Wb + (ncol + r) * 256 + kt * 64 + kc * 8);
      *reinterpret_cast<uint4*>(&Bs[r * 72 + kc * 8]) = vb;
    }
    __syncthreads();
#pragma unroll
    for (int ks = 0; ks < 2; ++ks) {
      bf16x8 af[4], bf[4];
#pragma unroll
      for (int m = 0; m < 4; ++m)
        af[m] = *reinterpret_cast<const bf16x8*>(&As[(waveM + m * 16 + (lane & 15)) * 72 + ks * 32 + (lane >> 4) * 8]);
#pragma unroll
      for (int n = 0; n < 4; ++n)
        bf[n] = *reinterpret_cast<const bf16x8*>(&Bs[(waveN + n * 16 + (lane & 15)) * 72 + ks * 32 + (lane >> 4) * 8]);
#pragma unroll
      for (int m = 0; m < 4; ++m)
#pragma unroll
        for (int n = 0; n < 4; ++n) acc[m][n] = mfma16(af[m], bf[n], acc[m][n]);
    }
  }
#pragma unroll
  for (int m = 0; m < 4; ++m)
#pragma unroll
    for (int n = 0; n < 4; ++n) {
      int j = ncol + waveN + n * 16 + (lane & 15);
      float bias_v = bias[j] * bscale;
      int h = j >> 5, d = j & 31;
      int i0 = bm + waveM + m * 16 + (lane >> 4) * 4;  // row of r=0 (mult of 4)
      int b = i0 >> 11, s = i0 & 2047;
      if (mat == 2) {
        ushort4 ww = *reinterpret_cast<const ushort4*>(&wb[s]);
        ushort4 pk;
        pk.x = f2bf((acc[m][n][0] + bias_v) * bfbits2f(ww.x));
        pk.y = f2bf((acc[m][n][1] + bias_v) * bfbits2f(ww.y));
        pk.z = f2bf((acc[m][n][2] + bias_v) * bfbits2f(ww.z));
        pk.w = f2bf((acc[m][n][3] + bias_v) * bfbits2f(ww.w));
        *reinterpret_cast<ushort4*>(&Vt[((b * NHEAD + h) * DK + d) * SEQ + s]) = pk;
      } else {
        unsigned short* dst = (mat == 0) ? Qb : Kb;
#pragma unroll
        for (int r = 0; r < 4; ++r)
          dst[((b * NHEAD + h) * SEQ + s + r) * DK + d] = f2bf(acc[m][n][r] + bias_v);
      }
    }
}

// ---------------- fused weighted attention (r8 + XCD affinity + VALU den) ----
// r8 passing structure (dbuf'd P scratch, LDS transport). Changes:
// 1) 1-D grid with XCD-affinity swizzle: the 64 q-tile blocks of each bh land
//    on ONE XCD (4 bh/XCD, 1.5MB << 4MB L2) -> K/V panels cached once per XCD
//    instead of 8x, cutting L2-miss latency at each step's chain head.
// 2) denominator on VALU from f32 p (8 FMA/lane/step + final shfl_xor g-reduce)
//    -> deletes 2 of 10 MFMAs and the 16B/lane wf load per step.
// 3) s_setprio(1) around the PV MFMA pair (T5, attn-positive per guide).
__global__ __launch_bounds__(256, 4) void attn_kernel(
    const unsigned short* __restrict__ Qb, const unsigned short* __restrict__ Kb,
    const unsigned short* __restrict__ Vt, const unsigned short* __restrict__ wb,
    unsigned short* __restrict__ AOb) {
  __shared__ float ol[4][32][36];
  __shared__ __align__(16) unsigned short ps[4][2][32][40];
  const int tid = threadIdx.x, lane = tid & 63, wid = tid >> 6;
  const int g = lane >> 4, lq = lane & 15;

  // XCD-affinity decode: xcd = bid%8 serves bh in [4*xcd, 4*xcd+4)
  const int bid = blockIdx.x;
  const int xcd = bid & 7, slot = bid >> 3;        // 256 slots per XCD
  const int bh = xcd * 4 + (slot >> 6);
  const int q0 = (slot & 63) * 32;

  const unsigned short* Qbh = Qb + bh * SEQ * DK;
  const unsigned short* Kbh = Kb + bh * SEQ * DK;
  const unsigned short* Vbh = Vt + bh * DK * SEQ;

  bf16x8 qf[2];
  qf[0] = *reinterpret_cast<const bf16x8*>(Qbh + (q0 + lq) * DK + g * 8);
  qf[1] = *reinterpret_cast<const bf16x8*>(Qbh + (q0 + 16 + lq) * DK + g * 8);

  f32x4 o[2][2] = {};   // [q-tile m][d-tile n]
  float dsum[2] = {0.f, 0.f};
  const f32x4 zero4 = {0.f, 0.f, 0.f, 0.f};
  const int sbase = wid * (SEQ / 4);

#pragma unroll 2
  for (int st = 0; st < (SEQ / 4) / 32; ++st) {
    const int s0 = sbase + st * 32;
    bf16x8 kf0 = *reinterpret_cast<const bf16x8*>(Kbh + (s0 + lq) * DK + g * 8);
    bf16x8 kf1 = *reinterpret_cast<const bf16x8*>(Kbh + (s0 + 16 + lq) * DK + g * 8);
    bf16x8 vf0 = *reinterpret_cast<const bf16x8*>(Vbh + (lq)      * SEQ + s0 + g * 8);
    bf16x8 vf1 = *reinterpret_cast<const bf16x8*>(Vbh + (16 + lq) * SEQ + s0 + g * 8);
    // w scalars for this lane's score rows: s = s0 + 4g + r (h=0), +16 (h=1)
    ushort4 wlo = *reinterpret_cast<const ushort4*>(wb + s0 + 4 * g);
    ushort4 whi = *reinterpret_cast<const ushort4*>(wb + s0 + 16 + 4 * g);
    float w0[4] = {bfbits2f(wlo.x), bfbits2f(wlo.y), bfbits2f(wlo.z), bfbits2f(wlo.w)};
    float w1[4] = {bfbits2f(whi.x), bfbits2f(whi.y), bfbits2f(whi.z), bfbits2f(whi.w)};

    unsigned short* pb = &ps[wid][st & 1][0][0];

#pragma unroll
    for (int m = 0; m < 2; ++m) {
      f32x4 sc0 = mfma16(kf0, qf[m], zero4);
      f32x4 sc1 = mfma16(kf1, qf[m], zero4);
      float p0[4], p1[4];
#pragma unroll
      for (int r = 0; r < 4; ++r) {
        p0[r] = __builtin_amdgcn_exp2f(sc0[r]);
        p1[r] = __builtin_amdgcn_exp2f(sc1[r]);
      }
      dsum[m] += w0[0] * p0[0] + w0[1] * p0[1] + w0[2] * p0[2] + w0[3] * p0[3]
               + w1[0] * p1[0] + w1[1] * p1[1] + w1[2] * p1[2] + w1[3] * p1[3];
      uint2 a0, a1;
      a0.x = cvtpk(p0[0], p0[1]); a0.y = cvtpk(p0[2], p0[3]);
      a1.x = cvtpk(p1[0], p1[1]); a1.y = cvtpk(p1[2], p1[3]);
      *reinterpret_cast<uint2*>(pb + (16 * m + lq) * 40 + g * 4)      = a0;
      *reinterpret_cast<uint2*>(pb + (16 * m + lq) * 40 + 16 + g * 4) = a1;
      bf16x8 pa = *reinterpret_cast<const bf16x8*>(pb + (16 * m + lq) * 40 + g * 8);
      __builtin_amdgcn_s_setprio(1);
      o[m][0] = mfma16(pa, vf0, o[m][0]);
      o[m][1] = mfma16(pa, vf1, o[m][1]);
      __builtin_amdgcn_s_setprio(0);
    }
  }

  // reduce den over the 4 g-lanes (lane bits 4,5) — all lanes end up with it
#pragma unroll
  for (int m = 0; m < 2; ++m) {
    float v = dsum[m];
    v += __shfl_xor(v, 16);
    v += __shfl_xor(v, 32);
    dsum[m] = v;
  }

  // stash partials into ol[wid]: [q32][d], denominator in col 32
#pragma unroll
  for (int m = 0; m < 2; ++m) {
#pragma unroll
    for (int r = 0; r < 4; ++r) {
      int q32 = 16 * m + 4 * g + r;
      ol[wid][q32][lq]      = o[m][0][r];
      ol[wid][q32][16 + lq] = o[m][1][r];
    }
    if (g == 0) ol[wid][16 * m + lq][32] = dsum[m];
  }
  __syncthreads();

  const int b = bh >> 3, h = bh & 7;
  for (int idx = tid; idx < 32 * 32; idx += 256) {
    int q = idx >> 5, d = idx & 31;
    float num = ol[0][q][d] + ol[1][q][d] + ol[2][q][d] + ol[3][q][d];
    float dd  = ol[0][q][32] + ol[1][q][32] + ol[2][q][32] + ol[3][q][32];
    AOb[(b * SEQ + q0 + q) * D_MODEL + h * DK + d] = f2bf(num / dd);
  }
}

// ---------------- output projection GEMM (fp32 out + bias) ----------------
__global__ __launch_bounds__(256) void out_gemm(
    const unsigned short* __restrict__ Ab, const unsigned short* __restrict__ Wob,
    const float* __restrict__ bo, float* __restrict__ out) {
  __shared__ __align__(16) unsigned short As[128 * 72];
  __shared__ __align__(16) unsigned short Bs[128 * 72];
  const int tid = threadIdx.x, lane = tid & 63, wid = tid >> 6;
  const int bm = blockIdx.x * 128;
  const int ncol = blockIdx.y * 128;
  const int waveM = (wid >> 1) * 64, waveN = (wid & 1) * 64;

  f32x4 acc[4][4] = {};
  for (int kt = 0; kt < 4; ++kt) {
    __syncthreads();
#pragma unroll
    for (int p = 0; p < 4; ++p) {
      int c = p * 256 + tid;
      int r = c >> 3, kc = c & 7;
      uint4 va = *reinterpret_cast<const uint4*>(Ab + (bm + r) * 256 + kt * 64 + kc * 8);
      *reinterpret_cast<uint4*>(&As[r * 72 + kc * 8]) = va;
      uint4 vb = *reinterpret_cast<const uint4*>(Wob + (ncol + r) * 256 + kt * 64 + kc * 8);
      *reinterpret_cast<uint4*>(&Bs[r * 72 + kc * 8]) = vb;
    }
    __syncthreads();
#pragma unroll
    for (int ks = 0; ks < 2; ++ks) {
      bf16x8 af[4], bf[4];
#pragma unroll
      for (int m = 0; m < 4; ++m)
        af[m] = *reinterpret_cast<const bf16x8*>(&As[(waveM + m * 16 + (lane & 15)) * 72 + ks * 32 + (lane >> 4) * 8]);
#pragma unroll
      for (int n = 0; n < 4; ++n)
        bf[n] = *reinterpret_cast<const bf16x8*>(&Bs[(waveN + n * 16 + (lane & 15)) * 72 + ks * 32 + (lane >> 4) * 8]);
#pragma unroll
      for (int m = 0; m < 4; ++m)
#pragma unroll
        for (int n = 0; n < 4; ++n) acc[m][n] = mfma16(af[m], bf[n], acc[m][n]);
    }
  }
#pragma unroll
  for (int m = 0; m < 4; ++m)
#pragma unroll
    for (int n = 0; n < 4; ++n) {
      int j = ncol + waveN + n * 16 + (lane & 15);
      float bias_v = bo[j];
#pragma unroll
      for (int r = 0; r < 4; ++r) {
        int i = bm + waveM + m * 16 + (lane >> 4) * 4 + r;
        out[i * D_MODEL + j] = acc[m][n][r] + bias_v;
      }
    }
}

// ---------------- launcher ----------------
extern "C" void kernel_launch(void* const* d_in, const int* in_sizes, int n_in,
                              void* d_out, int out_size, void* d_ws, size_t ws_size,
                              hipStream_t stream) {
  const float* x  = (const float*)d_in[0];
  const float* cx = (const float*)d_in[1];
  const float* Wq = (const float*)d_in[2];
  const float* bq = (const float*)d_in[3];
  const float* Wk = (const float*)d_in[4];
  const float* bk = (const float*)d_in[5];
  const float* Wv = (const float*)d_in[6];
  const float* bv = (const float*)d_in[7];
  const float* Wo = (const float*)d_in[8];
  const float* bo = (const float*)d_in[9];
  float* out = (float*)d_out;
  char* ws = (char*)d_ws;

  unsigned short* Qb  = (unsigned short*)(ws + (size_t)4  * 1024 * 1024);
  unsigned short* Kb  = (unsigned short*)(ws + (size_t)8  * 1024 * 1024);
  unsigned short* Vt  = (unsigned short*)(ws + (size_t)12 * 1024 * 1024);
  unsigned short* AOb = (unsigned short*)(ws + (size_t)16 * 1024 * 1024);
  unsigned short* Wqb = (unsigned short*)(ws + (size_t)20 * 1024 * 1024);
  unsigned short* Wkb = Wqb + 65536;
  unsigned short* Wvb = Wkb + 65536;
  unsigned short* Wob = Wvb + 65536;
  unsigned short* wb  = (unsigned short*)(ws + (size_t)21 * 1024 * 1024);

  prep_kernel<<<64, 256, 0, stream>>>(cx, Wq, Wk, Wv, Wo, Wqb, Wkb, Wvb, Wob, wb);
  qkv_gemm<<<dim3(64, 6), 256, 0, stream>>>(x, Wqb, Wkb, Wvb, bq, bk, bv, wb, Qb, Kb, Vt);
  attn_kernel<<<2048, 256, 0, stream>>>(Qb, Kb, Vt, wb, AOb);
  out_gemm<<<dim3(64, 2), 256, 0, stream>>>(AOb, Wob, bo, out);
}

// Round 14
// 82.659 us; speedup vs baseline: 1.1440x; 1.1440x over previous
//
#include <hip/hip_runtime.h>
#include <hip/hip_bf16.h>
#include <stdint.h>

#define D_MODEL 256
#define NHEAD   8
#define DK      32
#define BATCH   4
#define SEQ     2048
#define MROWS   (BATCH*SEQ)   // 8192

typedef float  f32x4  __attribute__((ext_vector_type(4)));
typedef __bf16 bf16x8 __attribute__((ext_vector_type(8)));

__device__ __forceinline__ unsigned short f2bf(float f) {
  unsigned int u = __float_as_uint(f);
  unsigned int r = (u + 0x7FFFu + ((u >> 16) & 1u)) >> 16;
  return (unsigned short)r;
}
__device__ __forceinline__ float bfbits2f(unsigned short b) {
  return __uint_as_float(((unsigned int)b) << 16);
}

__device__ __forceinline__ f32x4 mfma16(bf16x8 a, bf16x8 b, f32x4 c) {
  return __builtin_amdgcn_mfma_f32_16x16x32_bf16(a, b, c, 0, 0, 0);
}
__device__ __forceinline__ unsigned int cvtpk(float lo, float hi) {
  unsigned int r;
  asm("v_cvt_pk_bf16_f32 %0, %1, %2" : "=v"(r) : "v"(lo), "v"(hi));
  return r;
}

// scale folded into Wq/bq: (1/sqrt(32)) * log2(e)
#define QSCALE 0.2550599440097021f

// ---------------- fused QKV projection GEMM ----------------------------------
// W casts fused into B staging (no prep kernel). x cast fused into A staging.
// Q/K out: [bh][s][32]; V out: transposed + w-scaled: Vt[bh][d][s] = w_s*V[s][d]
// (w computed from cx, double-rounded through bf16 => bit-identical to the old
//  wb-based scaling, so num/den w-rounding still cancels exactly in attn).
// Blocks with blockIdx.y==4 also materialize wb[] (bf16 w) for attn's den.
__global__ __launch_bounds__(256) void qkv_gemm(
    const float* __restrict__ x, const float* __restrict__ cx,
    const float* __restrict__ Wq, const float* __restrict__ Wk,
    const float* __restrict__ Wv,
    const float* __restrict__ bq, const float* __restrict__ bk_, const float* __restrict__ bv,
    unsigned short* __restrict__ Qb, unsigned short* __restrict__ Kb,
    unsigned short* __restrict__ Vt, unsigned short* __restrict__ wb) {
  __shared__ __align__(16) unsigned short As[128 * 72];
  __shared__ __align__(16) unsigned short Bs[128 * 72];
  const int tid = threadIdx.x, lane = tid & 63, wid = tid >> 6;
  const int bm = blockIdx.x * 128;
  const int mat = blockIdx.y >> 1;
  const int ncol = (blockIdx.y & 1) * 128;
  const float* Wf = (mat == 0) ? Wq : ((mat == 1) ? Wk : Wv);
  const float* bias = (mat == 0) ? bq : ((mat == 1) ? bk_ : bv);
  const float bscale = (mat == 0) ? QSCALE : 1.0f;
  const int waveM = (wid >> 1) * 64, waveN = (wid & 1) * 64;

  // wb preamble: 64 blocks with y==4 each write 32 entries (no sync needed;
  // attn consumes wb only after this kernel completes, stream-ordered).
  if (blockIdx.y == 4 && tid < 32) {
    int s = blockIdx.x * 32 + tid;
    wb[s] = (s == 0) ? (unsigned short)0 : f2bf(fabsf(cx[s] - cx[s - 1]));
  }

  f32x4 acc[4][4] = {};
  for (int kt = 0; kt < 4; ++kt) {
    __syncthreads();
#pragma unroll
    for (int p = 0; p < 4; ++p) {
      int c = p * 256 + tid;
      int r = c >> 3, kc = c & 7;
      const float* xp = x + (size_t)(bm + r) * 256 + kt * 64 + kc * 8;
      float4 f0 = *reinterpret_cast<const float4*>(xp);
      float4 f1 = *reinterpret_cast<const float4*>(xp + 4);
      ushort4 h0, h1;
      h0.x = f2bf(f0.x); h0.y = f2bf(f0.y); h0.z = f2bf(f0.z); h0.w = f2bf(f0.w);
      h1.x = f2bf(f1.x); h1.y = f2bf(f1.y); h1.z = f2bf(f1.z); h1.w = f2bf(f1.w);
      *reinterpret_cast<ushort4*>(&As[r * 72 + kc * 8])     = h0;
      *reinterpret_cast<ushort4*>(&As[r * 72 + kc * 8 + 4]) = h1;
      const float* wp_ = Wf + (size_t)(ncol + r) * 256 + kt * 64 + kc * 8;
      float4 g0 = *reinterpret_cast<const float4*>(wp_);
      float4 g1 = *reinterpret_cast<const float4*>(wp_ + 4);
      ushort4 b0, b1;
      b0.x = f2bf(g0.x * bscale); b0.y = f2bf(g0.y * bscale);
      b0.z = f2bf(g0.z * bscale); b0.w = f2bf(g0.w * bscale);
      b1.x = f2bf(g1.x * bscale); b1.y = f2bf(g1.y * bscale);
      b1.z = f2bf(g1.z * bscale); b1.w = f2bf(g1.w * bscale);
      *reinterpret_cast<ushort4*>(&Bs[r * 72 + kc * 8])     = b0;
      *reinterpret_cast<ushort4*>(&Bs[r * 72 + kc * 8 + 4]) = b1;
    }
    __syncthreads();
#pragma unroll
    for (int ks = 0; ks < 2; ++ks) {
      bf16x8 af[4], bf[4];
#pragma unroll
      for (int m = 0; m < 4; ++m)
        af[m] = *reinterpret_cast<const bf16x8*>(&As[(waveM + m * 16 + (lane & 15)) * 72 + ks * 32 + (lane >> 4) * 8]);
#pragma unroll
      for (int n = 0; n < 4; ++n)
        bf[n] = *reinterpret_cast<const bf16x8*>(&Bs[(waveN + n * 16 + (lane & 15)) * 72 + ks * 32 + (lane >> 4) * 8]);
#pragma unroll
      for (int m = 0; m < 4; ++m)
#pragma unroll
        for (int n = 0; n < 4; ++n) acc[m][n] = mfma16(af[m], bf[n], acc[m][n]);
    }
  }
#pragma unroll
  for (int m = 0; m < 4; ++m) {
    int i0 = bm + waveM + m * 16 + (lane >> 4) * 4;  // row of r=0 (mult of 4)
    int b = i0 >> 11, s = i0 & 2047;
    float wv4[4] = {0.f, 0.f, 0.f, 0.f};
    if (mat == 2) {
      float cm = (s > 0) ? cx[s - 1] : 0.0f;
      float c0 = cx[s], c1 = cx[s + 1], c2 = cx[s + 2], c3 = cx[s + 3];
      wv4[0] = (s > 0) ? bfbits2f(f2bf(fabsf(c0 - cm))) : 0.0f;
      wv4[1] = bfbits2f(f2bf(fabsf(c1 - c0)));
      wv4[2] = bfbits2f(f2bf(fabsf(c2 - c1)));
      wv4[3] = bfbits2f(f2bf(fabsf(c3 - c2)));
    }
#pragma unroll
    for (int n = 0; n < 4; ++n) {
      int j = ncol + waveN + n * 16 + (lane & 15);
      float bias_v = bias[j] * bscale;
      int h = j >> 5, d = j & 31;
      if (mat == 2) {
        ushort4 pk;
        pk.x = f2bf((acc[m][n][0] + bias_v) * wv4[0]);
        pk.y = f2bf((acc[m][n][1] + bias_v) * wv4[1]);
        pk.z = f2bf((acc[m][n][2] + bias_v) * wv4[2]);
        pk.w = f2bf((acc[m][n][3] + bias_v) * wv4[3]);
        *reinterpret_cast<ushort4*>(&Vt[((b * NHEAD + h) * DK + d) * SEQ + s]) = pk;
      } else {
        unsigned short* dst = (mat == 0) ? Qb : Kb;
#pragma unroll
        for (int r = 0; r < 4; ++r)
          dst[((b * NHEAD + h) * SEQ + s + r) * DK + d] = f2bf(acc[m][n][r] + bias_v);
      }
    }
  }
}

// ---------------- fused weighted attention — VERBATIM round-8 (55.9us) -------
__global__ __launch_bounds__(256, 4) void attn_kernel(
    const unsigned short* __restrict__ Qb, const unsigned short* __restrict__ Kb,
    const unsigned short* __restrict__ Vt, const unsigned short* __restrict__ wb,
    unsigned short* __restrict__ AOb) {
  __shared__ float ol[4][32][36];
  __shared__ __align__(16) unsigned short ps[4][2][32][40];
  const int tid = threadIdx.x, lane = tid & 63, wid = tid >> 6;
  const int g = lane >> 4, lq = lane & 15;
  const int bh = blockIdx.y;
  const int q0 = blockIdx.x * 32;

  const unsigned short* Qbh = Qb + bh * SEQ * DK;
  const unsigned short* Kbh = Kb + bh * SEQ * DK;
  const unsigned short* Vbh = Vt + bh * DK * SEQ;

  bf16x8 qf[2];
  qf[0] = *reinterpret_cast<const bf16x8*>(Qbh + (q0 + lq) * DK + g * 8);
  qf[1] = *reinterpret_cast<const bf16x8*>(Qbh + (q0 + 16 + lq) * DK + g * 8);

  f32x4 o[2][2] = {};   // [q-tile m][d-tile n]
  f32x4 den[2] = {};
  const f32x4 zero4 = {0.f, 0.f, 0.f, 0.f};
  const int sbase = wid * (SEQ / 4);

#pragma unroll 2
  for (int st = 0; st < (SEQ / 4) / 32; ++st) {
    const int s0 = sbase + st * 32;
    bf16x8 kf0 = *reinterpret_cast<const bf16x8*>(Kbh + (s0 + lq) * DK + g * 8);
    bf16x8 kf1 = *reinterpret_cast<const bf16x8*>(Kbh + (s0 + 16 + lq) * DK + g * 8);

    unsigned short* pb = &ps[wid][st & 1][0][0];

#pragma unroll
    for (int m = 0; m < 2; ++m) {
      f32x4 sc0 = mfma16(kf0, qf[m], zero4);
      f32x4 sc1 = mfma16(kf1, qf[m], zero4);
      uint2 w0, w1;
      w0.x = cvtpk(__builtin_amdgcn_exp2f(sc0[0]), __builtin_amdgcn_exp2f(sc0[1]));
      w0.y = cvtpk(__builtin_amdgcn_exp2f(sc0[2]), __builtin_amdgcn_exp2f(sc0[3]));
      w1.x = cvtpk(__builtin_amdgcn_exp2f(sc1[0]), __builtin_amdgcn_exp2f(sc1[1]));
      w1.y = cvtpk(__builtin_amdgcn_exp2f(sc1[2]), __builtin_amdgcn_exp2f(sc1[3]));
      *reinterpret_cast<uint2*>(pb + (16 * m + lq) * 40 + g * 4)      = w0;
      *reinterpret_cast<uint2*>(pb + (16 * m + lq) * 40 + 16 + g * 4) = w1;
    }

    bf16x8 vf0 = *reinterpret_cast<const bf16x8*>(Vbh + (lq)      * SEQ + s0 + g * 8);
    bf16x8 vf1 = *reinterpret_cast<const bf16x8*>(Vbh + (16 + lq) * SEQ + s0 + g * 8);
    bf16x8 wf  = *reinterpret_cast<const bf16x8*>(wb + s0 + g * 8);

#pragma unroll
    for (int m = 0; m < 2; ++m) {
      bf16x8 pa = *reinterpret_cast<const bf16x8*>(pb + (16 * m + lq) * 40 + g * 8);
      o[m][0] = mfma16(pa, vf0, o[m][0]);
      o[m][1] = mfma16(pa, vf1, o[m][1]);
      den[m]  = mfma16(pa, wf,  den[m]);
    }
  }

  // stash partials into ol[wid]: [q32][d], denominator in col 32
#pragma unroll
  for (int m = 0; m < 2; ++m) {
#pragma unroll
    for (int r = 0; r < 4; ++r) {
      int q32 = 16 * m + 4 * g + r;
      ol[wid][q32][lq]      = o[m][0][r];
      ol[wid][q32][16 + lq] = o[m][1][r];
      if (lq == 0) ol[wid][q32][32] = den[m][r];
    }
  }
  __syncthreads();

  const int b = bh >> 3, h = bh & 7;
  for (int idx = tid; idx < 32 * 32; idx += 256) {
    int q = idx >> 5, d = idx & 31;
    float num = ol[0][q][d] + ol[1][q][d] + ol[2][q][d] + ol[3][q][d];
    float dd  = ol[0][q][32] + ol[1][q][32] + ol[2][q][32] + ol[3][q][32];
    AOb[(b * SEQ + q0 + q) * D_MODEL + h * DK + d] = f2bf(num / dd);
  }
}

// ---------------- output projection GEMM (128x64 tiles, full CU coverage) ----
// Wo cast fused into B staging. Grid (64,4) = 256 blocks = 1 block/CU.
__global__ __launch_bounds__(256) void out_gemm(
    const unsigned short* __restrict__ Ab, const float* __restrict__ Wo,
    const float* __restrict__ bo, float* __restrict__ out) {
  __shared__ __align__(16) unsigned short As[128 * 72];
  __shared__ __align__(16) unsigned short Bs[64 * 72];
  const int tid = threadIdx.x, lane = tid & 63, wid = tid >> 6;
  const int bm = blockIdx.x * 128;
  const int ncol = blockIdx.y * 64;
  const int waveM = wid * 32;

  f32x4 acc[2][4] = {};
  for (int kt = 0; kt < 4; ++kt) {
    __syncthreads();
#pragma unroll
    for (int p = 0; p < 4; ++p) {
      int c = p * 256 + tid;
      int r = c >> 3, kc = c & 7;
      uint4 va = *reinterpret_cast<const uint4*>(Ab + (size_t)(bm + r) * 256 + kt * 64 + kc * 8);
      *reinterpret_cast<uint4*>(&As[r * 72 + kc * 8]) = va;
    }
#pragma unroll
    for (int p = 0; p < 2; ++p) {
      int c = p * 256 + tid;
      int r = c >> 3, kc = c & 7;
      const float* wp_ = Wo + (size_t)(ncol + r) * 256 + kt * 64 + kc * 8;
      float4 g0 = *reinterpret_cast<const float4*>(wp_);
      float4 g1 = *reinterpret_cast<const float4*>(wp_ + 4);
      ushort4 b0, b1;
      b0.x = f2bf(g0.x); b0.y = f2bf(g0.y); b0.z = f2bf(g0.z); b0.w = f2bf(g0.w);
      b1.x = f2bf(g1.x); b1.y = f2bf(g1.y); b1.z = f2bf(g1.z); b1.w = f2bf(g1.w);
      *reinterpret_cast<ushort4*>(&Bs[r * 72 + kc * 8])     = b0;
      *reinterpret_cast<ushort4*>(&Bs[r * 72 + kc * 8 + 4]) = b1;
    }
    __syncthreads();
#pragma unroll
    for (int ks = 0; ks < 2; ++ks) {
      bf16x8 af[2], bf[4];
#pragma unroll
      for (int m = 0; m < 2; ++m)
        af[m] = *reinterpret_cast<const bf16x8*>(&As[(waveM + m * 16 + (lane & 15)) * 72 + ks * 32 + (lane >> 4) * 8]);
#pragma unroll
      for (int n = 0; n < 4; ++n)
        bf[n] = *reinterpret_cast<const bf16x8*>(&Bs[(n * 16 + (lane & 15)) * 72 + ks * 32 + (lane >> 4) * 8]);
#pragma unroll
      for (int m = 0; m < 2; ++m)
#pragma unroll
        for (int n = 0; n < 4; ++n) acc[m][n] = mfma16(af[m], bf[n], acc[m][n]);
    }
  }
#pragma unroll
  for (int m = 0; m < 2; ++m)
#pragma unroll
    for (int n = 0; n < 4; ++n) {
      int j = ncol + n * 16 + (lane & 15);
      float bias_v = bo[j];
#pragma unroll
      for (int r = 0; r < 4; ++r) {
        int i = bm + waveM + m * 16 + (lane >> 4) * 4 + r;
        out[(size_t)i * D_MODEL + j] = acc[m][n][r] + bias_v;
      }
    }
}

// ---------------- launcher ----------------
extern "C" void kernel_launch(void* const* d_in, const int* in_sizes, int n_in,
                              void* d_out, int out_size, void* d_ws, size_t ws_size,
                              hipStream_t stream) {
  const float* x  = (const float*)d_in[0];
  const float* cx = (const float*)d_in[1];
  const float* Wq = (const float*)d_in[2];
  const float* bq = (const float*)d_in[3];
  const float* Wk = (const float*)d_in[4];
  const float* bk = (const float*)d_in[5];
  const float* Wv = (const float*)d_in[6];
  const float* bv = (const float*)d_in[7];
  const float* Wo = (const float*)d_in[8];
  const float* bo = (const float*)d_in[9];
  float* out = (float*)d_out;
  char* ws = (char*)d_ws;

  unsigned short* Qb  = (unsigned short*)(ws + (size_t)4  * 1024 * 1024);
  unsigned short* Kb  = (unsigned short*)(ws + (size_t)8  * 1024 * 1024);
  unsigned short* Vt  = (unsigned short*)(ws + (size_t)12 * 1024 * 1024);
  unsigned short* AOb = (unsigned short*)(ws + (size_t)16 * 1024 * 1024);
  unsigned short* wb  = (unsigned short*)(ws + (size_t)21 * 1024 * 1024);

  qkv_gemm<<<dim3(64, 6), 256, 0, stream>>>(x, cx, Wq, Wk, Wv, bq, bk, bv, Qb, Kb, Vt, wb);
  attn_kernel<<<dim3(64, 32), 256, 0, stream>>>(Qb, Kb, Vt, wb, AOb);
  out_gemm<<<dim3(64, 4), 256, 0, stream>>>(AOb, Wo, bo, out);
}